// Round 1
// baseline (144.253 us; speedup 1.0000x reference)
//
#include <hip/hip_runtime.h>
#include <hip/hip_bf16.h>
#include <cstdint>
#include <cstddef>

#define NBATCH 8
#define NANCH 25500
#define MAXDET 300

typedef __bf16 bf16x8 __attribute__((ext_vector_type(8)));
typedef float floatx4 __attribute__((ext_vector_type(4)));
typedef unsigned long long ull;

// ---------------------------------------------------------------------------
// K1: conf = max_c(cls_c * obj), argmax class, threshold 0.1
// ---------------------------------------------------------------------------
#define CONF_TILE 64
__global__ __launch_bounds__(256) void conf_kernel(const float* __restrict__ preds,
                                                   float* __restrict__ conf,
                                                   int* __restrict__ cls, int total) {
  __shared__ float s[CONF_TILE * 85];
  int base = blockIdx.x * CONF_TILE;
  int nA = total - base; if (nA > CONF_TILE) nA = CONF_TILE;
  int n4 = (nA * 85) >> 2;
  const float4* g4 = (const float4*)(preds + (size_t)base * 85);
  float4* s4 = (float4*)s;
  for (int i = threadIdx.x; i < n4; i += 256) s4[i] = g4[i];
  __syncthreads();
  int lane16 = threadIdx.x & 15;
  int sub = threadIdx.x >> 4;
  #pragma unroll
  for (int r = 0; r < 4; ++r) {
    int a = r * 16 + sub;
    if (a < nA) {
      const float* row = s + a * 85;
      float obj = row[4];
      float best = -1.0f; int bc = 0;
      #pragma unroll
      for (int j = 0; j < 5; ++j) {
        int c = lane16 * 5 + j;
        float v = row[5 + c] * obj;    // exact IEEE mul, matches reference
        if (v > best) { best = v; bc = c; }
      }
      #pragma unroll
      for (int m = 1; m < 16; m <<= 1) {
        float ov = __shfl_xor(best, m, 64);
        int   oc = __shfl_xor(bc,   m, 64);
        if (ov > best || (ov == best && oc < bc)) { best = ov; bc = oc; }
      }
      if (lane16 == 0) {
        int idx = base + a;
        conf[idx] = (best > 0.1f) ? best : 0.0f;
        cls[idx] = bc;
      }
    }
  }
}

// ---------------------------------------------------------------------------
// K2: per-batch top-300 + NMS. One block (1024 threads) per batch.
// Histogram is prebuilt (512 bins, global) by the mega kernel; here we only
// do: wave-shuffle suffix-scan to find threshold bin T, one conf scan to
// compact candidates into LDS, branchless rank sort (exact top-300 by
// (value desc, idx asc) -- independent of bin granularity), then NMS.
// topv/topi live purely in LDS (no global round trip).
// fp contract OFF for bitwise-matching IOU.
// ---------------------------------------------------------------------------
#define TK_CAP 2048
__global__ __launch_bounds__(1024) void topk_nms_kernel(const float* __restrict__ conf,
                                                        const float* __restrict__ preds,
                                                        const int* __restrict__ cls,
                                                        const int* __restrict__ ghist,
                                                        float* __restrict__ cand_v, int* __restrict__ cand_i,
                                                        float* __restrict__ boxesWs, int* __restrict__ keepWs,
                                                        const float* __restrict__ orig_hw,
                                                        float* __restrict__ out, int N) {
  #pragma clang fp contract(off)
  __shared__ __align__(16) char smem[43008];
  int b = blockIdx.x;
  int t = threadIdx.x;

  // LDS layout:
  //  phase1: s_h @0 (2048), s_c @2048 (2048)  [dead after T found]
  //  phase2 overlay: mask @0 (12000), bo5 @12032 (6000), bxx @18048 (4800),
  //                  keepw @22848 (40), nzrow @22888 (40)
  //  persistent: tv @23040 (1200), ti @24256 (1200),
  //              lv_s @25600 (8192), li_s @33792 (8192), shv @41984
  int*   s_h  = (int*)smem;
  int*   s_c  = (int*)(smem + 2048);
  float* tv   = (float*)(smem + 23040);
  int*   ti   = (int*)(smem + 24256);
  float* lv_s = (float*)(smem + 25600);
  int*   li_s = (int*)(smem + 33792);
  int*   shv  = (int*)(smem + 41984);   // [0]=T, [1]=cand count

  // ----- phase 1: threshold find + compact + rank sort ---------------------
  int T, total;
  {
    if (t == 0) shv[1] = 0;
    if (t < 512) s_h[t] = ghist[b * 512 + t];
    for (int i = t; i < 300; i += 1024) { tv[i] = 0.0f; ti[i] = 0; }
    __syncthreads();
    // suffix-scan (cum from top bin) via in-wave shuffles: 512 bins = 8 waves
    int suff = 0;
    if (t < 512) {
      suff = s_h[t];
      int l = t & 63;
      #pragma unroll
      for (int d = 1; d < 64; d <<= 1) {
        int o = __shfl_down(suff, d, 64);
        if (l + d < 64) suff += o;
      }
    }
    __syncthreads();                              // all s_h[t] reads done
    if (t < 512 && (t & 63) == 0) s_h[t >> 6] = suff;  // wave-chunk totals
    __syncthreads();
    if (t < 512) {
      int w = t >> 6;
      int hi = 0;
      #pragma unroll
      for (int w2 = 1; w2 < 8; ++w2) if (w2 > w) hi += s_h[w2];
      s_c[t] = suff + hi;                         // c[t] = sum_{j>=t} hist[j]
    }
    __syncthreads();
    total = s_c[0];
    int target = total < 300 ? total : 300;
    if (t < 512) {
      int c = s_c[t];
      if (c >= target && (t == 511 || s_c[t + 1] < target)) shv[0] = t;  // unique
    }
    __syncthreads();
    T = shv[0];

    const float* cf = conf + (size_t)b * N;
    const float4* cf4 = (const float4*)cf;
    int N4 = N >> 2;                              // 25500/4 = 6375 exactly
    float* cv = cand_v + (size_t)b * N;
    int* ci = cand_i + (size_t)b * N;
    if (total > 0) {
      auto cand = [&](float v, int idx) {
        if (v > 0.1f) {
          unsigned bits = __float_as_uint(v);
          int bin = (int)((bits - 0x3D800000u) >> 16);
          if (bin > 511) bin = 511;
          if (bin >= T) {
            int pos = atomicAdd(&shv[1], 1);
            if (pos < TK_CAP) { lv_s[pos] = v; li_s[pos] = idx; }
            else { cv[pos] = v; ci[pos] = idx; }   // spill (not hit with this data)
          }
        }
      };
      for (int i4 = t; i4 < N4; i4 += 1024) {
        float4 v = cf4[i4];
        int i = i4 * 4;
        cand(v.x, i); cand(v.y, i + 1); cand(v.z, i + 2); cand(v.w, i + 3);
      }
    }
    __syncthreads();
    int K = shv[1];
    int Klds = K < TK_CAP ? K : TK_CAP;
    for (int i = t; i < K; i += 1024) {
      float v; int id;
      if (i < TK_CAP) { v = lv_s[i]; id = li_s[i]; }
      else            { v = cv[i];   id = ci[i];   }
      int rank = 0;
      #pragma unroll 8
      for (int j = 0; j < Klds; ++j) {               // LDS broadcast, branchless
        float vj = lv_s[j];
        int ij = li_s[j];
        int gt = vj > v;
        int eq = (vj == v) & (ij < id);
        rank += gt | eq;
      }
      for (int j = TK_CAP; j < K; ++j) {             // spill path (normally empty)
        float vj = cv[j];
        int ij = ci[j];
        int gt = vj > v;
        int eq = (vj == v) & (ij < id);
        rank += gt | eq;
      }
      if (rank < 300) { tv[rank] = v; ti[rank] = id; }
    }
  }
  __syncthreads();

  // ----- phase 2: NMS (LDS overlay; tv/ti persist above the overlay) ------
  {
    ull  (*mask)[5] = (ull(*)[5])smem;                     // 12000 B
    float (*bo5)[5] = (float(*)[5])(smem + 12032);         //  6000 B
    float (*bxx)[4] = (float(*)[4])(smem + 18048);         //  4800 B
    ull* keepw = (ull*)(smem + 22848);                     //    40 B
    ull* nzrow = (ull*)(smem + 22888);                     //    40 B
    if (t < 5) { keepw[t] = 0ULL; nzrow[t] = 0ULL; }
    __syncthreads();
    if (t < 300) {
      int i = ti[t];
      float v = tv[t];
      const float* p = preds + ((size_t)b * N + i) * 85;
      float cx = p[0], cy = p[1], w = p[2], h = p[3];
      float hw2 = w * 0.5f, hh2 = h * 0.5f;
      float x1 = cx - hw2, y1 = cy - hh2, x2 = cx + hw2, y2 = cy + hh2;
      bxx[t][0] = x1; bxx[t][1] = y1; bxx[t][2] = x2; bxx[t][3] = y2;
      size_t bi = ((size_t)(b * 300 + t)) * 4;
      boxesWs[bi + 0] = x1; boxesWs[bi + 1] = y1; boxesWs[bi + 2] = x2; boxesWs[bi + 3] = y2;
      int c = cls[(size_t)b * N + i];
      float off = (float)c * 4096.0f;
      float o0 = x1 + off, o1 = y1 + off, o2 = x2 + off, o3 = y2 + off;
      bo5[t][0] = o0; bo5[t][1] = o1; bo5[t][2] = o2; bo5[t][3] = o3;
      bo5[t][4] = (o2 - o0) * (o3 - o1);   // area from offset box, like reference
      if (v > 0.1f) atomicOr(&keepw[t >> 6], 1ULL << (t & 63));
    }
    __syncthreads();
    {
      int wv = t >> 6, ln = t & 63;        // 16 waves; tasks 0..9
      if (wv < 10) {
        int w = wv >> 1, half = wv & 1;
        int j = w * 64 + ln;
        int jc = j < 300 ? j : 0;
        float jb0 = bo5[jc][0], jb1 = bo5[jc][1], jb2 = bo5[jc][2], jb3 = bo5[jc][3], ja = bo5[jc][4];
        bool jv = j < 300;
        int iend = w * 64 + 64; if (iend > 300) iend = 300;
        int i0 = half * 150, i1 = i0 + 150; if (i1 > iend) i1 = iend;
        #pragma unroll 4
        for (int i = i0; i < i1; ++i) {
          float a0 = bo5[i][0], a1 = bo5[i][1], a2 = bo5[i][2], a3 = bo5[i][3], ai = bo5[i][4];
          float ltx = fmaxf(a0, jb0);
          float lty = fmaxf(a1, jb1);
          float rbx = fminf(a2, jb2);
          float rby = fminf(a3, jb3);
          float wx = fmaxf(rbx - ltx, 0.0f);
          float wy = fmaxf(rby - lty, 0.0f);
          float inter = wx * wy;
          float iou = inter / (ai + ja - inter + 1e-7f);
          ull bal = __ballot(jv && (j > i) && (iou > 0.6f));
          if (ln == 0) {
            mask[i][w] = bal;
            if (bal) atomicOr(&nzrow[i >> 6], 1ULL << (i & 63));
          }
        }
      }
    }
    __syncthreads();
    if (t == 0) {
      ull kw[5], nz[5];
      #pragma unroll
      for (int w = 0; w < 5; ++w) { kw[w] = keepw[w]; nz[w] = nzrow[w]; }
      #pragma unroll
      for (int w = 0; w < 5; ++w) {
        ull p = kw[w] & nz[w];
        while (p) {
          int l = __builtin_ctzll(p);
          p &= p - 1;
          int i = w * 64 + l;
          for (int w2 = w; w2 < 5; ++w2) {
            ull m = mask[i][w2];
            kw[w2] &= ~m;
            if (w2 == w) p &= ~m;
          }
        }
      }
      #pragma unroll
      for (int w = 0; w < 5; ++w) keepw[w] = kw[w];
    }
    __syncthreads();
    if (t < 300) {
      int kp = (int)((keepw[t >> 6] >> (t & 63)) & 1ULL);
      keepWs[b * 300 + t] = kp;
      float oh = orig_hw[b * 2 + 0], ow = orig_hw[b * 2 + 1];
      float gain = fminf(640.0f / oh, 640.0f / ow);
      float padx = (640.0f - ow * gain) * 0.5f;
      float pady = (640.0f - oh * gain) * 0.5f;
      float x1 = fminf(fmaxf((bxx[t][0] - padx) / gain, 0.0f), ow) / ow;
      float y1 = fminf(fmaxf((bxx[t][1] - pady) / gain, 0.0f), oh) / oh;
      float x2 = fminf(fmaxf((bxx[t][2] - padx) / gain, 0.0f), ow) / ow;
      float y2 = fminf(fmaxf((bxx[t][3] - pady) / gain, 0.0f), oh) / oh;
      size_t o = ((size_t)(b * 300 + t)) * 260;
      out[o + 0] = kp ? x1 : 0.0f;
      out[o + 1] = kp ? y1 : 0.0f;
      out[o + 2] = kp ? x2 : 0.0f;
      out[o + 3] = kp ? y2 : 0.0f;
    }
  }
}

// ---------------------------------------------------------------------------
// K3: fused (C,HW) -> (HW,C) transposes, fp32 -> bf16, 6 segments
// (4 feature levels x 8 batches + W1 + W2) in one launch, PLUS 64 histogram
// blocks (8 segments x 8 batches) building the 512-bin per-batch conf
// histogram via LDS + sparse global-atomic flush. The hist blocks ride along
// with the memory-bound transpose blocks -> near-free.
// ---------------------------------------------------------------------------
struct TransArgs {
  const float* src[6];
  __hip_bfloat16* dst[6];
  int C[6], HW[6], tx[6], tpb[6], start[6];
};

__global__ void transpose_all_kernel(TransArgs a, const float* __restrict__ conf,
                                     int* __restrict__ ghist, int hist_start) {
  __shared__ __align__(16) char msm[4352];
  int bid = blockIdx.x;
  if (bid >= hist_start) {
    // ---- histogram role ----
    int* sh = (int*)msm;                       // 512 bins
    int hb = bid - hist_start;                 // 0..63
    int b = hb >> 3, seg = hb & 7;
    int tid = threadIdx.y * 32 + threadIdx.x;  // 0..255
    sh[tid] = 0; sh[tid + 256] = 0;
    __syncthreads();
    const int N4 = NANCH >> 2;                 // 6375
    int i0 = (N4 * seg) >> 3, i1 = (N4 * (seg + 1)) >> 3;
    const float4* cf4 = (const float4*)(conf + (size_t)b * NANCH);
    auto histo = [&](float v) {
      if (v > 0.1f) {
        unsigned bits = __float_as_uint(v);
        int bin = (int)((bits - 0x3D800000u) >> 16);
        if (bin > 511) bin = 511;
        atomicAdd(&sh[bin], 1);
      }
    };
    for (int i = i0 + tid; i < i1; i += 256) {
      float4 v = cf4[i];
      histo(v.x); histo(v.y); histo(v.z); histo(v.w);
    }
    __syncthreads();
    int c0 = sh[tid], c1 = sh[tid + 256];
    if (c0) atomicAdd(&ghist[b * 512 + tid], c0);
    if (c1) atomicAdd(&ghist[b * 512 + tid + 256], c1);
    return;
  }
  // ---- transpose role ----
  float (*tile)[33] = (float(*)[33])msm;
  int s = 0;
  #pragma unroll
  for (int i = 1; i < 6; ++i) if (bid >= a.start[i]) s = i;
  int local = bid - a.start[s];
  int C = a.C[s], HW = a.HW[s], tx0 = a.tx[s], tpb = a.tpb[s];
  int b = local / tpb;
  int rem = local - b * tpb;
  int p0 = (rem % tx0) * 32;
  int c0 = (rem / tx0) * 32;
  const float* inb = a.src[s] + (size_t)b * C * HW;
  __hip_bfloat16* outb = a.dst[s] + (size_t)b * C * HW;
  int tx = threadIdx.x, ty = threadIdx.y;   // 32 x 8
  #pragma unroll
  for (int k = 0; k < 32; k += 8) {
    int c = c0 + ty + k, p = p0 + tx;
    if (c < C && p < HW) tile[ty + k][tx] = inb[(size_t)c * HW + p];
  }
  __syncthreads();
  #pragma unroll
  for (int k = 0; k < 32; k += 8) {
    int p = p0 + ty + k, c = c0 + tx;
    if (p < HW && c < C) outb[(size_t)p * C + c] = __float2bfloat16(tile[tx][ty + k]);
  }
}

// ---------------------------------------------------------------------------
// K4: ROI-align 1x1 over 4 levels from HWC bf16 features -> bf16 fmat rows.
// XCD-affinity: b = blockIdx.x & 7 so every block of batch b lands on XCD b
// (blocks round-robin across the 8 XCDs) -> batch's 3.1 MB of features stays
// L2-resident for all 300 ROIs.
// ---------------------------------------------------------------------------
__global__ __launch_bounds__(256) void roi_kernel(const float* __restrict__ boxes,
                                                  const __hip_bfloat16* __restrict__ fT1, const __hip_bfloat16* __restrict__ fT2,
                                                  const __hip_bfloat16* __restrict__ fT3, const __hip_bfloat16* __restrict__ fT4,
                                                  __hip_bfloat16* __restrict__ f) {
  int b = blockIdx.x & 7;
  int r = blockIdx.x >> 3;
  __shared__ int t_off[4][16];
  __shared__ float t_w[4][16];
  int t = threadIdx.x;
  const int Hs[4] = {80, 40, 20, 10};
  const int Cs[4] = {128, 256, 512, 1024};
  const float ss[4] = {0.125f, 0.0625f, 0.03125f, 0.015625f};
  size_t bbase = ((size_t)(b * 300 + r)) * 4;
  float bx0 = boxes[bbase + 0];
  float by0 = boxes[bbase + 1];
  float bx1 = boxes[bbase + 2];
  float by1 = boxes[bbase + 3];
  if (t < 64) {
    int lv = t >> 4, k = t & 15, pp = k >> 2, nb = k & 3;
    float s = ss[lv];
    int H = Hs[lv], W = Hs[lv], C = Cs[lv];
    float b0 = bx0 * s, b1 = by0 * s, b2 = bx1 * s, b3 = by1 * s;
    float w = fmaxf(b2 - b0, 1.0f), h = fmaxf(b3 - b1, 1.0f);
    const float offv[2] = {0.5f, 1.5f};
    float px = b0 + offv[pp & 1] * (w * 0.5f);
    float py = b1 + offv[pp >> 1] * (h * 0.5f);
    float y = fminf(fmaxf(py, 0.0f), (float)(H - 1));
    float x = fminf(fmaxf(px, 0.0f), (float)(W - 1));
    int y0 = (int)floorf(y), x0 = (int)floorf(x);
    int y1 = min(y0 + 1, H - 1), x1 = min(x0 + 1, W - 1);
    float ly = y - (float)y0, lx = x - (float)x0;
    int yy = (nb & 2) ? y1 : y0;
    int xx = (nb & 1) ? x1 : x0;
    float wy = (nb & 2) ? ly : (1.0f - ly);
    float wx = (nb & 1) ? lx : (1.0f - lx);
    t_off[lv][k] = (yy * W + xx) * C;
    t_w[lv][k] = wy * wx;
  }
  __syncthreads();
  const __hip_bfloat16* bases[4] = {
    fT1 + (size_t)b * 6400 * 128,
    fT2 + (size_t)b * 1600 * 256,
    fT3 + (size_t)b * 400 * 512,
    fT4 + (size_t)b * 100 * 1024
  };
  __hip_bfloat16* frow = f + (size_t)(b * 300 + r) * 1920;
  int cbase = 0;
  #pragma unroll
  for (int lv = 0; lv < 4; ++lv) {
    int C = Cs[lv];
    const __hip_bfloat16* base = bases[lv];
    for (int c = t; c < C; c += 256) {
      float acc = 0.0f;
      #pragma unroll
      for (int k = 0; k < 16; ++k)
        acc += t_w[lv][k] * __bfloat162float(base[t_off[lv][k] + c]);
      frow[cbase + c] = __float2bfloat16(acc * 0.25f);
    }
    cbase += C;
  }
}

// ---------------------------------------------------------------------------
// K5/K6: staged bf16 MFMA GEMM. BM=BN=BK=64, 4 waves/block (each 32x32),
// double-buffered LDS via global_load_lds(16B) with both-sides XOR swizzle.
// ---------------------------------------------------------------------------
#define GLDS16(gp, lp) __builtin_amdgcn_global_load_lds( \
    (const __attribute__((address_space(1))) unsigned int*)(gp), \
    (__attribute__((address_space(3))) unsigned int*)(lp), 16, 0, 0)

__global__ __launch_bounds__(256) void gemm_tile_kernel(const __hip_bfloat16* __restrict__ A,
                                                        const __hip_bfloat16* __restrict__ BT,
                                                        const float* __restrict__ bias,
                                                        __hip_bfloat16* __restrict__ Cb,
                                                        float* __restrict__ Cf,
                                                        const int* __restrict__ keep,
                                                        int M, int N, int K, int ldc, int coff) {
  __shared__ __hip_bfloat16 sA[2][64 * 64];
  __shared__ __hip_bfloat16 sB[2][64 * 64];
  int tid = threadIdx.x;
  int bm = blockIdx.x * 64, bn = blockIdx.y * 64;
  int wave = tid >> 6, lane = tid & 63;
  int wr = wave >> 1, wc = wave & 1;
  int idx16 = lane & 15, kb = lane >> 4;
  floatx4 acc[2][2] = {};
  int nt = K >> 6;

  auto stage = [&](int buf, int t) {
    int k0 = t << 6;
    #pragma unroll
    for (int i = 0; i < 2; ++i) {
      int c = tid + i * 256;
      int row = c >> 3, cc = c & 7;
      int scc = cc ^ (row & 7);
      GLDS16(A + (size_t)(bm + row) * K + k0 + scc * 8,
             (char*)&sA[buf][0] + c * 16);
    }
    #pragma unroll
    for (int i = 0; i < 2; ++i) {
      int c = tid + i * 256;
      int row = c >> 3, cc = c & 7;
      int scc = cc ^ (row & 7);
      GLDS16(BT + (size_t)(bn + row) * K + k0 + scc * 8,
             (char*)&sB[buf][0] + c * 16);
    }
  };

  stage(0, 0);
  asm volatile("s_waitcnt vmcnt(0)" ::: "memory");
  __syncthreads();
  int cur = 0;
  for (int t = 0; t < nt; ++t) {
    if (t + 1 < nt) stage(cur ^ 1, t + 1);
    const char* Ab = (const char*)&sA[cur][0];
    const char* Bb = (const char*)&sB[cur][0];
    #pragma unroll
    for (int s = 0; s < 2; ++s) {
      bf16x8 af[2], bg[2];
      #pragma unroll
      for (int m = 0; m < 2; ++m) {
        int row = wr * 32 + m * 16 + idx16;
        int chunk = s * 4 + kb;
        af[m] = *(const bf16x8*)(Ab + row * 128 + ((chunk ^ (row & 7)) * 16));
      }
      #pragma unroll
      for (int n = 0; n < 2; ++n) {
        int row = wc * 32 + n * 16 + idx16;
        int chunk = s * 4 + kb;
        bg[n] = *(const bf16x8*)(Bb + row * 128 + ((chunk ^ (row & 7)) * 16));
      }
      #pragma unroll
      for (int m = 0; m < 2; ++m)
        #pragma unroll
        for (int n = 0; n < 2; ++n)
          acc[m][n] = __builtin_amdgcn_mfma_f32_16x16x32_bf16(af[m], bg[n], acc[m][n], 0, 0, 0);
    }
    asm volatile("s_waitcnt vmcnt(0)" ::: "memory");
    __syncthreads();
    cur ^= 1;
  }
  int col = lane & 15, rb4 = (lane >> 4) * 4;
  #pragma unroll
  for (int m = 0; m < 2; ++m) {
    #pragma unroll
    for (int n = 0; n < 2; ++n) {
      #pragma unroll
      for (int r = 0; r < 4; ++r) {
        int orow = bm + wr * 32 + m * 16 + rb4 + r;
        int ocol = bn + wc * 32 + n * 16 + col;
        if (orow >= M) continue;
        float v = acc[m][n][r] + bias[ocol];
        v = (v >= 0.0f) ? v : 0.01f * v;
        if (Cb) Cb[(size_t)orow * N + ocol] = __float2bfloat16(v);
        if (Cf) {
          float km = keep ? (keep[orow] ? 1.0f : 0.0f) : 1.0f;
          Cf[(size_t)orow * ldc + coff + ocol] = v * km;
        }
      }
    }
  }
}

// ---------------------------------------------------------------------------
extern "C" void kernel_launch(void* const* d_in, const int* in_sizes, int n_in,
                              void* d_out, int out_size, void* d_ws, size_t ws_size,
                              hipStream_t stream) {
  (void)in_sizes; (void)n_in; (void)out_size; (void)ws_size;
  const float* preds  = (const float*)d_in[0];
  const float* feat1  = (const float*)d_in[1];
  const float* feat2  = (const float*)d_in[2];
  const float* feat3  = (const float*)d_in[3];
  const float* feat4  = (const float*)d_in[4];
  const float* orighw = (const float*)d_in[5];
  const float* W1     = (const float*)d_in[6];
  const float* b1     = (const float*)d_in[7];
  const float* W2     = (const float*)d_in[8];
  const float* b2     = (const float*)d_in[9];
  float* out = (float*)d_out;

  char* ws = (char*)d_ws;
  size_t off = 0;
  auto alloc = [&](size_t bytes) -> void* {
    void* p = ws + off;
    off = (off + bytes + 255) & ~(size_t)255;
    return p;
  };
  const int BN = NBATCH * NANCH;   // 204000
  float* conf   = (float*)alloc((size_t)BN * 4);
  int*   cls    = (int*)  alloc((size_t)BN * 4);
  float* cand_v = (float*)alloc((size_t)BN * 4);
  int*   cand_i = (int*)  alloc((size_t)BN * 4);
  int*   ghist  = (int*)  alloc((size_t)NBATCH * 512 * 4);
  float* boxes  = (float*)alloc((size_t)NBATCH * 300 * 4 * 4);
  int*   keep   = (int*)  alloc((size_t)NBATCH * 300 * 4);
  __hip_bfloat16* fT1  = (__hip_bfloat16*)alloc((size_t)NBATCH * 6400 * 128 * 2);
  __hip_bfloat16* fT2  = (__hip_bfloat16*)alloc((size_t)NBATCH * 1600 * 256 * 2);
  __hip_bfloat16* fT3  = (__hip_bfloat16*)alloc((size_t)NBATCH * 400 * 512 * 2);
  __hip_bfloat16* fT4  = (__hip_bfloat16*)alloc((size_t)NBATCH * 100 * 1024 * 2);
  __hip_bfloat16* fmat = (__hip_bfloat16*)alloc((size_t)2400 * 1920 * 2);
  __hip_bfloat16* h1b  = (__hip_bfloat16*)alloc((size_t)2400 * 256 * 2);
  __hip_bfloat16* W1T  = (__hip_bfloat16*)alloc((size_t)256 * 1920 * 2);
  __hip_bfloat16* W2T  = (__hip_bfloat16*)alloc((size_t)256 * 256 * 2);

  hipMemsetAsync(ghist, 0, (size_t)NBATCH * 512 * 4, stream);

  conf_kernel<<<(BN + CONF_TILE - 1) / CONF_TILE, 256, 0, stream>>>(preds, conf, cls, BN);

  // fused transposes (4 feature levels x 8 batches + W1 + W2) + 64 hist blocks
  TransArgs ta;
  ta.src[0] = feat1; ta.dst[0] = fT1; ta.C[0] = 128;  ta.HW[0] = 6400; ta.tx[0] = 200;
  ta.src[1] = feat2; ta.dst[1] = fT2; ta.C[1] = 256;  ta.HW[1] = 1600; ta.tx[1] = 50;
  ta.src[2] = feat3; ta.dst[2] = fT3; ta.C[2] = 512;  ta.HW[2] = 400;  ta.tx[2] = 13;
  ta.src[3] = feat4; ta.dst[3] = fT4; ta.C[3] = 1024; ta.HW[3] = 100;  ta.tx[3] = 4;
  ta.src[4] = W1;    ta.dst[4] = W1T; ta.C[4] = 1920; ta.HW[4] = 256;  ta.tx[4] = 8;
  ta.src[5] = W2;    ta.dst[5] = W2T; ta.C[5] = 256;  ta.HW[5] = 256;  ta.tx[5] = 8;
  int total_blocks = 0;
  for (int s = 0; s < 6; ++s) {
    int ty = (ta.C[s] + 31) / 32;
    int nbatch = (s < 4) ? NBATCH : 1;
    ta.tpb[s] = ta.tx[s] * ty;
    ta.start[s] = total_blocks;
    total_blocks += ta.tpb[s] * nbatch;
  }
  transpose_all_kernel<<<total_blocks + 64, dim3(32, 8), 0, stream>>>(ta, conf, ghist, total_blocks);

  topk_nms_kernel<<<NBATCH, 1024, 0, stream>>>(conf, preds, cls, ghist, cand_v, cand_i,
                                               boxes, keep, orighw, out, NANCH);
  roi_kernel<<<2400, 256, 0, stream>>>(boxes, fT1, fT2, fT3, fT4, fmat);
  gemm_tile_kernel<<<dim3(38, 4), 256, 0, stream>>>(fmat, W1T, b1, h1b, nullptr, nullptr,
                                                    2400, 256, 1920, 0, 0);
  gemm_tile_kernel<<<dim3(38, 4), 256, 0, stream>>>(h1b, W2T, b2, nullptr, out, keep,
                                                    2400, 256, 256, 260, 4);
}